// Round 12
// baseline (131.347 us; speedup 1.0000x reference)
//
#include <hip/hip_runtime.h>
#include <math.h>

#define NN 8192
#define DD 64
#define EE 64
#define NB 2
#define THRESH 0.7f
#define ISPLIT 4
#define ISPAN (NN / ISPLIT)   // 2048
#define LOG2E 1.4426950408889634f

typedef __attribute__((ext_vector_type(8))) short bf16x8;
typedef __attribute__((ext_vector_type(4))) float f32x4;
typedef _Float16 f16x4 __attribute__((ext_vector_type(4)));
typedef _Float16 f16x8 __attribute__((ext_vector_type(8)));
typedef __fp16 half2v __attribute__((ext_vector_type(2)));

static __device__ __forceinline__ short f2bf(float x) {  // RNE
    unsigned u = __float_as_uint(x);
    unsigned r = (u + 0x7fffu + ((u >> 16) & 1u)) >> 16;
    return (short)r;
}
static __device__ __forceinline__ unsigned pk_f16(float a, float b) {
    half2v h = __builtin_amdgcn_cvt_pkrtz(a, b);
    return __builtin_bit_cast(unsigned, h);
}
static __device__ __forceinline__ float f16lo(unsigned u) {
    half2v h = __builtin_bit_cast(half2v, u);
    return (float)h[0];
}
static __device__ __forceinline__ float f16hi(unsigned u) {
    half2v h = __builtin_bit_cast(half2v, u);
    return (float)h[1];
}

// ---------------------------------------------------------------------------
// Prep: blocks [0,128): P = U@W via MFMA + U -> bf16 (round-8 verified).
//       blocks [128,256): es16f fragment-major, g-PAIRED (round-11 verified):
//       es16f[((c16*4+gp)*64 + lane)*8 + (g&1)*4 + e] = es[16g+(lane&15)][16c16+4*(lane>>4)+e]
// ---------------------------------------------------------------------------
__global__ __launch_bounds__(256) void prep_kernel(const float* __restrict__ U,
                                                   const float* __restrict__ W,
                                                   const float* __restrict__ S,
                                                   const float* __restrict__ prof,
                                                   short* __restrict__ P_bf,
                                                   short* __restrict__ U_bf,
                                                   _Float16* __restrict__ es16f) {
    __shared__ float smem[64 * 132 + 128];  // 34.3 KB (covers both roles)
    const int t = threadIdx.x;
    const f32x4 zero = (f32x4){0.f, 0.f, 0.f, 0.f};

    if (blockIdx.x < 128) {
        // ---- P = U@W with 16x16x32 bf16 MFMA ----
        float* WT = smem;  // [64][68] transposed W (+68 pad: 2-way alias only)
        for (int x = 0; x < 16; ++x) {
            const int idx = x * 256 + t;     // idx = k*64 + f
            const int k = idx >> 6, f = idx & 63;
            WT[f * 68 + k] = W[idx];
        }
        __syncthreads();

        const int w = t >> 6, lane = t & 63, q = lane >> 4, ln = lane & 15;
        const int r0 = blockIdx.x * 64 + w * 16;

        bf16x8 a[2];
#pragma unroll
        for (int ks = 0; ks < 2; ++ks) {
            const float4 u0 = *(const float4*)(U + (r0 + ln) * EE + ks * 32 + q * 8);
            const float4 u1 = *(const float4*)(U + (r0 + ln) * EE + ks * 32 + q * 8 + 4);
            bf16x8 v;
            v[0] = f2bf(u0.x); v[1] = f2bf(u0.y); v[2] = f2bf(u0.z); v[3] = f2bf(u0.w);
            v[4] = f2bf(u1.x); v[5] = f2bf(u1.y); v[6] = f2bf(u1.z); v[7] = f2bf(u1.w);
            a[ks] = v;
            *(bf16x8*)(U_bf + (r0 + ln) * EE + ks * 32 + q * 8) = v;
        }
        bf16x8 b[4][2];
#pragma unroll
        for (int ct = 0; ct < 4; ++ct)
#pragma unroll
            for (int ks = 0; ks < 2; ++ks) {
                const float* wp = WT + (ct * 16 + ln) * 68 + ks * 32 + q * 8;
                const float4 w0 = *(const float4*)wp;
                const float4 w1 = *(const float4*)(wp + 4);
                bf16x8 v;
                v[0] = f2bf(w0.x); v[1] = f2bf(w0.y); v[2] = f2bf(w0.z); v[3] = f2bf(w0.w);
                v[4] = f2bf(w1.x); v[5] = f2bf(w1.y); v[6] = f2bf(w1.z); v[7] = f2bf(w1.w);
                b[ct][ks] = v;
            }
#pragma unroll
        for (int ct = 0; ct < 4; ++ct) {
            f32x4 s = __builtin_amdgcn_mfma_f32_16x16x32_bf16(a[0], b[ct][0], zero, 0, 0, 0);
            s = __builtin_amdgcn_mfma_f32_16x16x32_bf16(a[1], b[ct][1], s, 0, 0, 0);
#pragma unroll
            for (int r = 0; r < 4; ++r)
                P_bf[(r0 + 4 * q + r) * EE + ct * 16 + ln] = f2bf(s[r]);
        }
    } else {
        float* tr = smem;           // [64][132]
        float* gl = smem + 8448;    // [128]
        const int bi = blockIdx.x - 128;  // 0..127
        const int b = bi >> 6;
        const int i0 = (bi & 63) * 128;
        if (t < 128) gl[t] = fmaxf(prof[b * NN + i0 + t] - THRESH, 0.f);
        __syncthreads();
#pragma unroll
        for (int k = 0; k < 8; ++k) {
            const int idx = k * 256 + t;  // 2048 = 128 i x 16 c4
            const int i = idx >> 4, c4 = idx & 15;
            const float g = gl[i];
            const float4 s = ((const float4*)S)[(b * NN + i0 + i) * 16 + c4];
            tr[(c4 * 4 + 0) * 132 + i] = s.x * g;
            tr[(c4 * 4 + 1) * 132 + i] = s.y * g;
            tr[(c4 * 4 + 2) * 132 + i] = s.z * g;
            tr[(c4 * 4 + 3) * 132 + i] = s.w * g;
        }
        __syncthreads();
#pragma unroll
        for (int pass = 0; pass < 4; ++pass) {
            const int d = pass * 16 + (t >> 4);   // within-b row 0..63
            const int i8 = t & 15;                // 8-element i-group 0..15
            const float4 a = *(const float4*)&tr[d * 132 + i8 * 8];
            const float4 c = *(const float4*)&tr[d * 132 + i8 * 8 + 4];
            const int g   = b * 4 + (d >> 4);
            const int c16 = (i0 >> 4) + (i8 >> 1);
            const int q0  = 2 * (i8 & 1);
            const int gp  = g >> 1, glo = g & 1;
            _Float16* base = es16f +
                ((size_t)((c16 * 4 + gp) * 64 + q0 * 16 + (d & 15))) * 8 + glo * 4;
            uint2 v0, v1;
            v0.x = pk_f16(a.x, a.y); v0.y = pk_f16(a.z, a.w);
            v1.x = pk_f16(c.x, c.y); v1.y = pk_f16(c.z, c.w);
            *(uint2*)base = v0;           // q = q0
            *(uint2*)(base + 128) = v1;   // q = q0+1
        }
    }
}

// ---------------------------------------------------------------------------
// Transfer v4: barrier-free, JBLK=32 (2 jt/wave). acc halves to 64 regs ->
// ~80 spare VGPRs so the compiler can hoist the ping-pong prefetch (round-11
// was 248/256 regs and sank loads to point-of-use -> 1400 cyc stalls/chunk).
// Block owns 32 j; 4 waves partition i-chunks (c mod 4). No LDS, no sync.
// Grid (256, ISPLIT=4) = 1024 blocks.
// ---------------------------------------------------------------------------
__global__ __launch_bounds__(256, 2) void transfer_kernel(const short* __restrict__ P_bf,
                                                          const short* __restrict__ U_bf,
                                                          const _Float16* __restrict__ es16f,
                                                          const float* __restrict__ bias_p,
                                                          unsigned short* __restrict__ part) {
    const int t = threadIdx.x;
    const int w = t >> 6;
    const int lane = t & 63;
    const int q = lane >> 4;
    const int ln = lane & 15;
    const int j0 = blockIdx.x * 32;
    const int i_base = blockIdx.y * ISPAN;
    const int c16_base = i_base >> 4;
    const float nb = -bias_p[0] * LOG2E;
    const f32x4 zero = (f32x4){0.f, 0.f, 0.f, 0.f};

    // U B-fragments for the 2 j-tiles
    bf16x8 uf[2][2];
#pragma unroll
    for (int jt = 0; jt < 2; ++jt)
#pragma unroll
        for (int ks = 0; ks < 2; ++ks)
            uf[jt][ks] = *(const bf16x8*)(U_bf + (j0 + jt * 16 + ln) * EE + ks * 32 + q * 8);

    // acc[jt][g] lane(q,ln): leaked[j = j0+jt*16+4q+r][bd = 16g+ln]
    f32x4 acc[2][8];
#pragma unroll
    for (int jt = 0; jt < 2; ++jt)
#pragma unroll
        for (int g = 0; g < 8; ++g) acc[jt][g] = zero;

    auto loadP = [&](int c, bf16x8* pf) {
        const int ic = i_base + c * 16;
#pragma unroll
        for (int ks = 0; ks < 2; ++ks)
            pf[ks] = *(const bf16x8*)(P_bf + (ic + ln) * EE + ks * 32 + q * 8);
    };
    auto loadE = [&](int c, uint4* ef) {
        const _Float16* ep = es16f + (size_t)(c16_base + c) * 2048;
#pragma unroll
        for (int gp = 0; gp < 4; ++gp)
            ef[gp] = *(const uint4*)(ep + gp * 512 + lane * 8);  // 1KB/instr
    };
    auto body = [&](int c, const bf16x8* pf, const uint4* ef) {
        const int ic = i_base + c * 16;
        const int doff = ic - j0;
        const bool dg = (unsigned)doff < 32u;
        const int djt = doff >> 4;
        f16x4 esf[8];
#pragma unroll
        for (int gp = 0; gp < 4; ++gp) {
            const f16x8 full = __builtin_bit_cast(f16x8, ef[gp]);
            esf[2 * gp]     = __builtin_shufflevector(full, full, 0, 1, 2, 3);
            esf[2 * gp + 1] = __builtin_shufflevector(full, full, 4, 5, 6, 7);
        }
#pragma unroll
        for (int jt = 0; jt < 2; ++jt) {
            f32x4 s = __builtin_amdgcn_mfma_f32_16x16x32_bf16(pf[0], uf[jt][0], zero, 0, 0, 0);
            s = __builtin_amdgcn_mfma_f32_16x16x32_bf16(pf[1], uf[jt][1], s, 0, 0, 0);
            float T[4];
#pragma unroll
            for (int r = 0; r < 4; ++r)
                T[r] = __builtin_amdgcn_rcpf(
                    1.f + __builtin_amdgcn_exp2f(fmaf(s[r], -LOG2E, nb)));
            if (dg && jt == djt) {  // diagonal 16x16 sub-tile: zero i==j
                const int dd = ln - 4 * q;
#pragma unroll
                for (int r = 0; r < 4; ++r) T[r] = (dd == r) ? 0.f : T[r];
            }
            uint2 pw;
            pw.x = pk_f16(T[0], T[1]);
            pw.y = pk_f16(T[2], T[3]);
            const f16x4 pa = __builtin_bit_cast(f16x4, pw);
#pragma unroll
            for (int g = 0; g < 8; ++g)
                acc[jt][g] = __builtin_amdgcn_mfma_f32_16x16x16f16(pa, esf[g], acc[jt][g], 0, 0, 0);
        }
    };

    // wave handles chunks c = w, w+4, ... (32 chunks); explicit ping-pong.
    const int NCHW = (ISPAN / 16) / 4;  // 32
    bf16x8 pfa[2], pfb[2];
    uint4 efa[4], efb[4];
    int c = w;
    loadP(c, pfa);
    loadE(c, efa);
    for (int it = 0; it < NCHW; it += 2) {
        loadP(c + 4, pfb);
        loadE(c + 4, efb);
        body(c, pfa, efa);
        if (it + 2 < NCHW) {
            loadP(c + 8, pfa);
            loadE(c + 8, efa);
        }
        body(c + 4, pfb, efb);
        c += 8;
    }

    // epilogue: per-wave fp16 partial tile [2jt][8g][64lane][4r] = 8KB.
    unsigned short* pb = part +
        (size_t)(((blockIdx.y * 256 + blockIdx.x) * 4) + w) * 4096;
#pragma unroll
    for (int jt = 0; jt < 2; ++jt)
#pragma unroll
        for (int g = 0; g < 8; ++g) {
            uint2 v;
            v.x = pk_f16(acc[jt][g][0], acc[jt][g][1]);
            v.y = pk_f16(acc[jt][g][2], acc[jt][g][3]);
            *(uint2*)(pb + ((jt * 8 + g) * 64 + lane) * 4) = v;
        }
}

// ---------------------------------------------------------------------------
// Reduce: out = S + sum over 16 wave-tiles (4y x 4w) per (jx, g).
// grid (256, 4): blockIdx.y picks g = 2*gh2 + u; threads: wp=(t>>6) ->
// jt = wp&1, u = wp>>1. 1024 blocks x 256.
// ---------------------------------------------------------------------------
__global__ __launch_bounds__(256) void reduce_kernel(const unsigned short* __restrict__ part,
                                                     const float* __restrict__ S,
                                                     float* __restrict__ out) {
    const int t = threadIdx.x;
    const int jx = blockIdx.x;        // 0..255
    const int gh2 = blockIdx.y;       // 0..3
    const int lane = t & 63, wp = t >> 6;
    const int jt = wp & 1, u = wp >> 1;
    const int q = lane >> 4, ln = lane & 15;
    const int g = gh2 * 2 + u;        // 0..7

    float acc[4];
#pragma unroll
    for (int r = 0; r < 4; ++r) acc[r] = 0.f;

#pragma unroll
    for (int y = 0; y < ISPLIT; ++y)
#pragma unroll
        for (int wv = 0; wv < 4; ++wv) {
            const unsigned short* pb = part +
                (size_t)(((y * 256 + jx) * 4) + wv) * 4096;
            const uint2 v = *(const uint2*)(pb + ((jt * 8 + g) * 64 + lane) * 4);
            acc[0] += f16lo(v.x); acc[1] += f16hi(v.x);
            acc[2] += f16lo(v.y); acc[3] += f16hi(v.y);
        }

    const int bd = 16 * g + ln;
    const int b = bd >> 6, d = bd & 63;
#pragma unroll
    for (int r = 0; r < 4; ++r) {
        const int j = jx * 32 + jt * 16 + 4 * q + r;
        const int idx = (b * NN + j) * DD + d;
        out[idx] = S[idx] + acc[r];
    }
}

// ---------------------------------------------------------------------------
extern "C" void kernel_launch(void* const* d_in, const int* in_sizes, int n_in,
                              void* d_out, int out_size, void* d_ws, size_t ws_size,
                              hipStream_t stream) {
    const float* states = (const float*)d_in[0];  // [B,N,D]
    const float* prof   = (const float*)d_in[1];  // [B,N]
    const float* emb    = (const float*)d_in[2];  // [N,E]
    const float* W      = (const float*)d_in[3];  // [1,E,E]
    const float* bias   = (const float*)d_in[4];  // [1]
    float* out = (float*)d_out;

    short* P_bf = (short*)d_ws;                     // 1 MB
    short* U_bf = P_bf + NN * EE;                   // 1 MB
    _Float16* es16f = (_Float16*)(U_bf + NN * EE);  // 2 MB (fragment-major, g-paired)
    unsigned short* part = (unsigned short*)((short*)es16f + (size_t)NB * 64 * NN);  // 33.6 MB

    prep_kernel<<<256, 256, 0, stream>>>(emb, W, states, prof, P_bf, U_bf, es16f);
    transfer_kernel<<<dim3(256, ISPLIT), 256, 0, stream>>>(P_bf, U_bf, es16f, bias, part);
    reduce_kernel<<<dim3(256, 4), 256, 0, stream>>>(part, states, out);
}

// Round 13
// 108.488 us; speedup vs baseline: 1.2107x; 1.2107x over previous
//
#include <hip/hip_runtime.h>
#include <math.h>

#define NN 8192
#define DD 64
#define EE 64
#define NB 2
#define THRESH 0.7f
#define JT 64
#define IC 64
#define ISPLIT 8
#define ISPAN (NN / ISPLIT)
#define LOG2E 1.4426950408889634f

typedef __attribute__((ext_vector_type(8))) short bf16x8;
typedef __attribute__((ext_vector_type(4))) float f32x4;
typedef __fp16 half2v __attribute__((ext_vector_type(2)));

static __device__ __forceinline__ short f2bf(float x) {  // RNE
    unsigned u = __float_as_uint(x);
    unsigned r = (u + 0x7fffu + ((u >> 16) & 1u)) >> 16;
    return (short)r;
}
static __device__ __forceinline__ unsigned pack_bf_trunc(float lo, float hi) {
    return __builtin_amdgcn_perm(__float_as_uint(hi), __float_as_uint(lo), 0x07060302u);
}
static __device__ __forceinline__ unsigned pk_f16(float a, float b) {
    half2v h = __builtin_amdgcn_cvt_pkrtz(a, b);
    return __builtin_bit_cast(unsigned, h);
}
static __device__ __forceinline__ float f16lo(unsigned u) {
    half2v h = __builtin_bit_cast(half2v, u);
    return (float)h[0];
}
static __device__ __forceinline__ float f16hi(unsigned u) {
    half2v h = __builtin_bit_cast(half2v, u);
    return (float)h[1];
}

// ---------------------------------------------------------------------------
// Prep: blocks [0,128): P = U@W via MFMA + U -> bf16.
//       blocks [128,256): es in FRAGMENT-MAJOR tiles es_f[cg][g][ks][lane][8]
//       (coalesced consumer loads; fixes the 16KB-stride gather of the
//       row-major layout — round-6/7 diagnosis).
// ---------------------------------------------------------------------------
__global__ __launch_bounds__(256) void prep_kernel(const float* __restrict__ U,
                                                   const float* __restrict__ W,
                                                   const float* __restrict__ S,
                                                   const float* __restrict__ prof,
                                                   short* __restrict__ P_bf,
                                                   short* __restrict__ U_bf,
                                                   short* __restrict__ es_f) {
    __shared__ float smem[64 * 132 + 128];  // 34.3 KB (covers both roles)
    const int t = threadIdx.x;
    const f32x4 zero = (f32x4){0.f, 0.f, 0.f, 0.f};

    if (blockIdx.x < 128) {
        // ---- P = U@W with 16x16x32 bf16 MFMA ----
        float* WT = smem;  // [64][68] transposed W (+68 pad: 2-way alias only)
        for (int x = 0; x < 16; ++x) {
            const int idx = x * 256 + t;     // idx = k*64 + f
            const int k = idx >> 6, f = idx & 63;
            WT[f * 68 + k] = W[idx];
        }
        __syncthreads();

        const int w = t >> 6, lane = t & 63, q = lane >> 4, ln = lane & 15;
        const int r0 = blockIdx.x * 64 + w * 16;

        bf16x8 a[2];
#pragma unroll
        for (int ks = 0; ks < 2; ++ks) {
            const float4 u0 = *(const float4*)(U + (r0 + ln) * EE + ks * 32 + q * 8);
            const float4 u1 = *(const float4*)(U + (r0 + ln) * EE + ks * 32 + q * 8 + 4);
            bf16x8 v;
            v[0] = f2bf(u0.x); v[1] = f2bf(u0.y); v[2] = f2bf(u0.z); v[3] = f2bf(u0.w);
            v[4] = f2bf(u1.x); v[5] = f2bf(u1.y); v[6] = f2bf(u1.z); v[7] = f2bf(u1.w);
            a[ks] = v;
            *(bf16x8*)(U_bf + (r0 + ln) * EE + ks * 32 + q * 8) = v;
        }
        bf16x8 b[4][2];
#pragma unroll
        for (int ct = 0; ct < 4; ++ct)
#pragma unroll
            for (int ks = 0; ks < 2; ++ks) {
                const float* wp = WT + (ct * 16 + ln) * 68 + ks * 32 + q * 8;
                const float4 w0 = *(const float4*)wp;
                const float4 w1 = *(const float4*)(wp + 4);
                bf16x8 v;
                v[0] = f2bf(w0.x); v[1] = f2bf(w0.y); v[2] = f2bf(w0.z); v[3] = f2bf(w0.w);
                v[4] = f2bf(w1.x); v[5] = f2bf(w1.y); v[6] = f2bf(w1.z); v[7] = f2bf(w1.w);
                b[ct][ks] = v;
            }
#pragma unroll
        for (int ct = 0; ct < 4; ++ct) {
            f32x4 s = __builtin_amdgcn_mfma_f32_16x16x32_bf16(a[0], b[ct][0], zero, 0, 0, 0);
            s = __builtin_amdgcn_mfma_f32_16x16x32_bf16(a[1], b[ct][1], s, 0, 0, 0);
#pragma unroll
            for (int r = 0; r < 4; ++r)
                P_bf[(r0 + 4 * q + r) * EE + ct * 16 + ln] = f2bf(s[r]);
        }
    } else {
        float* tr = smem;           // [64][132]
        float* gl = smem + 8448;    // [128]
        const int bi = blockIdx.x - 128;  // 0..127
        const int b = bi >> 6;
        const int i0 = (bi & 63) * 128;
        if (t < 128) gl[t] = fmaxf(prof[b * NN + i0 + t] - THRESH, 0.f);
        __syncthreads();
#pragma unroll
        for (int k = 0; k < 8; ++k) {
            const int idx = k * 256 + t;  // 2048 = 128 i x 16 c4
            const int i = idx >> 4, c4 = idx & 15;
            const float g = gl[i];
            const float4 s = ((const float4*)S)[(b * NN + i0 + i) * 16 + c4];
            tr[(c4 * 4 + 0) * 132 + i] = s.x * g;
            tr[(c4 * 4 + 1) * 132 + i] = s.y * g;
            tr[(c4 * 4 + 2) * 132 + i] = s.z * g;
            tr[(c4 * 4 + 3) * 132 + i] = s.w * g;
        }
        __syncthreads();
#pragma unroll
        for (int pass = 0; pass < 4; ++pass) {
            const int d = pass * 16 + (t >> 4);   // within-b row 0..63
            const int i8 = t & 15;                // 8-element i-group 0..15
            const float4 a = *(const float4*)&tr[d * 132 + i8 * 8];
            const float4 c = *(const float4*)&tr[d * 132 + i8 * 8 + 4];
            bf16x8 v;
            v[0] = f2bf(a.x); v[1] = f2bf(a.y); v[2] = f2bf(a.z); v[3] = f2bf(a.w);
            v[4] = f2bf(c.x); v[5] = f2bf(c.y); v[6] = f2bf(c.z); v[7] = f2bf(c.w);
            // fragment-major address
            const int cg = (bi & 63) * 2 + (i8 >> 3);  // 64-i chunk
            const int ks = (i8 >> 2) & 1;
            const int q  = i8 & 3;
            const int g  = b * 4 + (d >> 4);
            const int lane = q * 16 + (d & 15);
            *(bf16x8*)(es_f + ((((cg * 8 + g) * 2 + ks) << 9) + lane * 8)) = v;
        }
    }
}

// ---------------------------------------------------------------------------
// Transfer: round-7/8 verified winner: grid (128, 8), 256 threads,
// fragment-major coalesced es loads, LDS TT exchange, double-buffered.
// ---------------------------------------------------------------------------
__global__ __launch_bounds__(256, 3) void transfer_kernel(const short* __restrict__ P_bf,
                                                          const short* __restrict__ U_bf,
                                                          const short* __restrict__ es_f,
                                                          const float* __restrict__ bias_p,
                                                          unsigned short* __restrict__ part) {
    // T in MFMA-A fragment order, double-buffered: [buf][tile][lane][8 shorts]
    __shared__ __align__(16) short TT[2][8 * 64 * 8];  // 16 KB

    const int t = threadIdx.x;
    const int w = t >> 6;
    const int lane = t & 63;
    const int q = lane >> 4;
    const int ln = lane & 15;
    const int j0 = blockIdx.x * JT;
    const int i_base = blockIdx.y * ISPAN;
    const int cg_base = blockIdx.y * (ISPAN / 64);
    const float nb = -bias_p[0] * LOG2E;

    // U B-fragments resident for the whole kernel
    bf16x8 uf[4][2];
#pragma unroll
    for (int jt = 0; jt < 4; ++jt)
#pragma unroll
        for (int ks = 0; ks < 2; ++ks)
            uf[jt][ks] = *(const bf16x8*)(U_bf + (j0 + jt * 16 + ln) * EE + ks * 32 + q * 8);

    f32x4 acc[4][2];
#pragma unroll
    for (int jm = 0; jm < 4; ++jm)
#pragma unroll
        for (int c = 0; c < 2; ++c) acc[jm][c] = (f32x4){0.f, 0.f, 0.f, 0.f};
    const f32x4 zero = (f32x4){0.f, 0.f, 0.f, 0.f};

    // producer TT slot: i_local=16w+4q+r -> ks=(w>>1), q'=(2w+(q>>1))&3, half=(q&1)
    const int ks_w = w >> 1;
    const int qp = (2 * w + (q >> 1)) & 3;
    const int ttw_off = (ks_w * 64 + qp * 16 + ln) * 2 + (q & 1);  // uint2 units

    auto load_p = [&](int cc, bf16x8* pf) {
        const int i0 = i_base + cc * IC;
#pragma unroll
        for (int ks = 0; ks < 2; ++ks)
            pf[ks] = *(const bf16x8*)(P_bf + (i0 + w * 16 + ln) * EE + ks * 32 + q * 8);
    };
    auto load_es = [&](int cc, bf16x8 (*bfr)[2]) {
        const int cg = cg_base + cc;
#pragma unroll
        for (int c = 0; c < 2; ++c) {
            const int g = w * 2 + c;
            const short* er = es_f + (((cg * 8 + g) * 2) << 9) + lane * 8;
#pragma unroll
            for (int ks = 0; ks < 2; ++ks)
                bfr[c][ks] = *(const bf16x8*)(er + (ks << 9));
        }
    };
    auto phase_a = [&](int cc, const bf16x8* pf, short* tt) {
        const int i0 = i_base + cc * IC;
        const bool dg = (i0 == j0);
#pragma unroll
        for (int jt = 0; jt < 4; ++jt) {
            f32x4 s = __builtin_amdgcn_mfma_f32_16x16x32_bf16(pf[0], uf[jt][0], zero, 0, 0, 0);
            s = __builtin_amdgcn_mfma_f32_16x16x32_bf16(pf[1], uf[jt][1], s, 0, 0, 0);
            float T[4];
#pragma unroll
            for (int r = 0; r < 4; ++r)
                T[r] = __builtin_amdgcn_rcpf(
                    1.f + __builtin_amdgcn_exp2f(fmaf(s[r], -LOG2E, nb)));
            if (dg && jt == w) {  // diagonal 16x16 sub-tile
                const int rr = ln - 4 * q;
                if (rr >= 0 && rr < 4) T[rr] = 0.f;
            }
            uint2 pk;
            pk.x = pack_bf_trunc(T[0], T[1]);
            pk.y = pack_bf_trunc(T[2], T[3]);
            ((uint2*)tt)[jt * 256 + ttw_off] = pk;
        }
    };
    auto phase_b = [&](const bf16x8 (*bfr)[2], const short* tt) {
#pragma unroll
        for (int jm = 0; jm < 4; ++jm)
#pragma unroll
            for (int ks = 0; ks < 2; ++ks) {
                const bf16x8 af = *(const bf16x8*)(tt + ((jm * 2 + ks) * 64 + lane) * 8);
                acc[jm][0] = __builtin_amdgcn_mfma_f32_16x16x32_bf16(af, bfr[0][ks], acc[jm][0], 0, 0, 0);
                acc[jm][1] = __builtin_amdgcn_mfma_f32_16x16x32_bf16(af, bfr[1][ks], acc[jm][1], 0, 0, 0);
            }
    };

    // prologue
    bf16x8 pfA[2], pfB[2], bfA[2][2], bfB[2][2];
    load_p(0, pfA);
    load_es(0, bfA);
    load_p(1, pfB);
    phase_a(0, pfA, TT[0]);
    __syncthreads();  // TT[0] ready

    const int NCH = ISPAN / IC;  // 16
#pragma unroll
    for (int c = 0; c < NCH; c += 2) {
        // even iter: A(c+1)->TT1 || B(c)<-TT0
        if (c + 1 < NCH) load_es(c + 1, bfB);
        if (c + 2 < NCH) load_p(c + 2, pfA);
        if (c + 1 < NCH) phase_a(c + 1, pfB, TT[1]);
        phase_b(bfA, TT[0]);
        __syncthreads();
        // odd iter: A(c+2)->TT0 || B(c+1)<-TT1
        if (c + 2 < NCH) load_es(c + 2, bfA);
        if (c + 3 < NCH) load_p(c + 3, pfB);
        if (c + 2 < NCH) phase_a(c + 2, pfA, TT[0]);
        if (c + 1 < NCH) phase_b(bfB, TT[1]);
        __syncthreads();
    }

    // epilogue: fp16 partials in [jm-plane][thread] layout (coalesced both ways)
    unsigned short* pb = part + (size_t)(blockIdx.y * (NN / JT) + blockIdx.x) * 8192;
#pragma unroll
    for (int jm = 0; jm < 4; ++jm) {
        uint4 v;
        v.x = pk_f16(acc[jm][0][0], acc[jm][0][1]);
        v.y = pk_f16(acc[jm][0][2], acc[jm][0][3]);
        v.z = pk_f16(acc[jm][1][0], acc[jm][1][1]);
        v.w = pk_f16(acc[jm][1][2], acc[jm][1][3]);
        *(uint4*)(pb + jm * 2048 + t * 8) = v;
    }
}

// ---------------------------------------------------------------------------
// Reduce: out[b][j][d] = state + sum_y partial_y. grid (128, 4) x 256
// (512 blocks, one jm-plane each).
// ---------------------------------------------------------------------------
__global__ __launch_bounds__(256) void reduce_kernel(const unsigned short* __restrict__ part,
                                                     const float* __restrict__ S,
                                                     float* __restrict__ out) {
    const int t = threadIdx.x;
    const int jx = blockIdx.x;   // 0..127
    const int jm = blockIdx.y;   // 0..3
    const int w = t >> 6, lane = t & 63, q = lane >> 4, ln = lane & 15;

    float acc[2][4];
#pragma unroll
    for (int c = 0; c < 2; ++c)
#pragma unroll
        for (int r = 0; r < 4; ++r) acc[c][r] = 0.f;

#pragma unroll
    for (int y = 0; y < ISPLIT; ++y) {
        const unsigned short* pb = part + (size_t)(y * (NN / JT) + jx) * 8192;
        const uint4 v = *(const uint4*)(pb + jm * 2048 + t * 8);  // coalesced
        acc[0][0] += f16lo(v.x); acc[0][1] += f16hi(v.x);
        acc[0][2] += f16lo(v.y); acc[0][3] += f16hi(v.y);
        acc[1][0] += f16lo(v.z); acc[1][1] += f16hi(v.z);
        acc[1][2] += f16lo(v.w); acc[1][3] += f16hi(v.w);
    }
#pragma unroll
    for (int c = 0; c < 2; ++c) {
        const int g = w * 2 + c;
        const int bb = g >> 2, dt = g & 3;
        const int j = jx * 64 + jm * 16 + q * 4;
#pragma unroll
        for (int r = 0; r < 4; ++r) {
            const int idx = (bb * NN + j + r) * DD + dt * 16 + ln;
            out[idx] = S[idx] + acc[c][r];
        }
    }
}

// ---------------------------------------------------------------------------
extern "C" void kernel_launch(void* const* d_in, const int* in_sizes, int n_in,
                              void* d_out, int out_size, void* d_ws, size_t ws_size,
                              hipStream_t stream) {
    const float* states = (const float*)d_in[0];  // [B,N,D]
    const float* prof   = (const float*)d_in[1];  // [B,N]
    const float* emb    = (const float*)d_in[2];  // [N,E]
    const float* W      = (const float*)d_in[3];  // [1,E,E]
    const float* bias   = (const float*)d_in[4];  // [1]
    float* out = (float*)d_out;

    short* P_bf = (short*)d_ws;                 // 1 MB
    short* U_bf = P_bf + NN * EE;               // 1 MB
    short* es_f = U_bf + NN * EE;               // 2 MB (fragment-major tiles)
    unsigned short* part = (unsigned short*)(es_f + (size_t)NB * 64 * NN);  // 16.8 MB

    prep_kernel<<<256, 256, 0, stream>>>(emb, W, states, prof, P_bf, U_bf, es_f);
    transfer_kernel<<<dim3(NN / JT, ISPLIT), 256, 0, stream>>>(P_bf, U_bf, es_f, bias, part);
    reduce_kernel<<<dim3(NN / JT, 4), 256, 0, stream>>>(part, states, out);
}